// Round 7
// baseline (315.441 us; speedup 1.0000x reference)
//
#include <hip/hip_runtime.h>
#include <hip/hip_fp16.h>

#define B_   8
#define S_   4096
#define DD_  1024   // dst nodes
#define DIM_ 512
#define SCALE 0.044194173824159216f  // 1/sqrt(512)
#define PPN  ((size_t)B_ * DD_ * DIM_)   // Pp slice stride (halfwords/elems)

typedef __bf16 bf16x8 __attribute__((ext_vector_type(8)));
typedef float  floatx4 __attribute__((ext_vector_type(4)));

__device__ inline unsigned short f2bf(float f) {
    union { float f; unsigned int u; } v; v.f = f;
    unsigned int r = v.u + 0x7fffu + ((v.u >> 16) & 1u);  // RNE
    return (unsigned short)(r >> 16);
}
__device__ inline float bf2f(unsigned short h) {
    union { unsigned int u; float f; } v; v.u = ((unsigned int)h) << 16;
    return v.f;
}
__device__ inline uint4 cvt8(const float* __restrict__ g) {
    float4 f0 = *(const float4*)g;
    float4 f1 = *(const float4*)(g + 4);
    unsigned short tmp[8] = {f2bf(f0.x), f2bf(f0.y), f2bf(f0.z), f2bf(f0.w),
                             f2bf(f1.x), f2bf(f1.y), f2bf(f1.z), f2bf(f1.w)};
    return *(const uint4*)tmp;
}
// async global->LDS, 16B per lane; lds base must be wave-uniform
__device__ inline void async16(unsigned short* lds, const unsigned short* g) {
    __builtin_amdgcn_global_load_lds(
        (const __attribute__((address_space(1))) void*)g,
        (__attribute__((address_space(3))) void*)lds, 16, 0, 0);
}

template <int N> __device__ inline void vwait() {
    if constexpr (N == 0)       asm volatile("s_waitcnt vmcnt(0)"  ::: "memory");
    else if constexpr (N == 4)  asm volatile("s_waitcnt vmcnt(4)"  ::: "memory");
    else if constexpr (N == 6)  asm volatile("s_waitcnt vmcnt(6)"  ::: "memory");
    else if constexpr (N == 8)  asm volatile("s_waitcnt vmcnt(8)"  ::: "memory");
    else if constexpr (N == 10) asm volatile("s_waitcnt vmcnt(10)" ::: "memory");
    else                        asm volatile("s_waitcnt vmcnt(12)" ::: "memory");
}
#define SBAR   __builtin_amdgcn_s_barrier()
#define SCHED0 __builtin_amdgcn_sched_barrier(0)

// ===========================================================================
// 256x256xK pipelined mainloop, B-OPERAND DIRECT-TO-REGISTER.
// BK=64, 512 threads = 8 waves (2M x 4N), per-wave output 128x64 (acc[8][4]).
// A staged in LDS (swizzled, dbuf [2][2kh][256][32] = 64 KiB); B fragments
// gathered straight from global: wave wn owns rows [wn*64,wn*64+64) and lane
// (fr,fk) loads its exact bf16x8 frag with one global_load_dwordx4 from the
// NATURAL row-major layout (16 rows x 64B segments, L2-resident panels).
// Removes 8 of 24 ds_read_b128/wave/tile (LDS floor 2304->1536 cyc/CU/tile)
// and all stgB staging; B values identical, MFMA order identical.
// Per tile vm ops: ph1 stgA(kt+1,k1)2, ph2 gatherB(kt,k1)4,
// ph3 stgA(kt+2,k0)2, ph4 gatherB(kt+1,k0)4 = 12 in flight steady.
// Manual waits cover only A-LDS cross-wave readiness (wait BEFORE barrier,
// dependent ds_read after); B-value waits are compiler-inserted:
//   end-ph1: vwait<8 if kt==0 else 12> -> A(kt,kk1) resident (read in ph2)
//   end-ph3: vwait<12 | 10 at nk-2>    -> A(kt+1,kk0) resident (read in ph4)
//   last tile: vwait<0> at end-ph1 (full drain; epilogue LDS-overlay safe).
// Ledger verified op-by-op for kt=0,1,steady,nk-2,nk-1.
// ===========================================================================
__device__ inline void mainloop256(unsigned short* As,
                                   const unsigned short* __restrict__ Ap, size_t lda,
                                   const unsigned short* __restrict__ Bp, size_t ldb,
                                   int nk, floatx4 (&acc)[8][4]) {
    const int t = threadIdx.x, lane = t & 63, w = t >> 6;
    const int wm = w >> 2, wn = w & 3;
    const int fr = lane & 15;
    const int swz  = (((lane >> 4) ^ ((fr >> 1) & 3)) << 3);   // A read-side slot XOR
    const int csrc = (((t & 3) ^ ((t >> 3) & 3)) << 3);        // A source-side inverse

    const unsigned short* gA = Ap + (size_t)(t >> 2) * lda + csrc;
    const unsigned short* pB = Bp + (size_t)(wn * 64 + fr) * ldb + (lane >> 4) * 8;
    unsigned short* ldsA = As + w * 512;   // wave-uniform; +lane*16B implicit

    auto stgA = [&](int buf, int kt, int kh) {
        const unsigned short* g = gA + (size_t)kt * 64 + kh * 32;
        async16(ldsA + buf * 16384 + kh * 8192,        g);
        async16(ldsA + buf * 16384 + kh * 8192 + 4096, g + (size_t)128 * lda);
    };
    auto gatherB = [&](bf16x8 (&dst)[4], int kt, int kh) {
#pragma unroll
        for (int n = 0; n < 4; ++n) {
            uint4 v = *(const uint4*)(pB + (size_t)n * 16 * ldb + kt * 64 + kh * 32);
            dst[n] = *(const bf16x8*)&v;
        }
    };

    // prologue: A tile0 (kk0,kk1) + tile1 kk0 [6 ops] + B(0,kk0) [4 ops]
    stgA(0, 0, 0); stgA(0, 0, 1); stgA(1, 1, 0);
    bf16x8 bA[4], bB[4];
    gatherB(bA, 0, 0);
    vwait<8>();                     // drains A(0,kk0) exactly
    SCHED0;
    SBAR;

    const int arow = wm * 128 + fr;
    bf16x8 a0[4], a1[4], a2[4], a3[4];
#pragma unroll
    for (int i = 0; i < 4; ++i) a0[i] = *(const bf16x8*)&As[(arow + i * 16) * 32 + swz];

    for (int kt = 0; kt < nk; ++kt) {
        const int cur = kt & 1, base = cur * 16384;
        const bool sA = kt + 1 < nk, sB = kt + 2 < nk;
        // ---- ph1: MFMA mh0/kk0 (a0,bA); prefetch a1; stage A(kt+1,k1) ----
        if (sA) stgA(cur ^ 1, kt + 1, 1);
        SCHED0;
        __builtin_amdgcn_s_setprio(1);
#pragma unroll
        for (int i = 0; i < 4; ++i)
            a1[i] = *(const bf16x8*)&As[base + (arow + 64 + i * 16) * 32 + swz];
#pragma unroll
        for (int i = 0; i < 4; ++i)
#pragma unroll
            for (int j = 0; j < 4; ++j)
                acc[i][j] = __builtin_amdgcn_mfma_f32_16x16x32_bf16(a0[i], bA[j], acc[i][j], 0, 0, 0);
        __builtin_amdgcn_s_setprio(0);
        if (sA) { if (kt == 0) vwait<8>(); else vwait<12>(); } else vwait<0>();
        SBAR;
        // ---- ph2: MFMA mh1/kk0 (a1,bA); prefetch a2; gather B(kt,k1) ----
        gatherB(bB, kt, 1);
        SCHED0;
        __builtin_amdgcn_s_setprio(1);
#pragma unroll
        for (int i = 0; i < 4; ++i)
            a2[i] = *(const bf16x8*)&As[base + 8192 + (arow + i * 16) * 32 + swz];
#pragma unroll
        for (int i = 0; i < 4; ++i)
#pragma unroll
            for (int j = 0; j < 4; ++j)
                acc[4 + i][j] = __builtin_amdgcn_mfma_f32_16x16x32_bf16(a1[i], bA[j], acc[4 + i][j], 0, 0, 0);
        __builtin_amdgcn_s_setprio(0);
        SBAR;
        // ---- ph3: MFMA mh0/kk1 (a2,bB); prefetch a3; stage A(kt+2,k0) ----
        if (sB) stgA(cur, kt + 2, 0);
        SCHED0;
        __builtin_amdgcn_s_setprio(1);
#pragma unroll
        for (int i = 0; i < 4; ++i)
            a3[i] = *(const bf16x8*)&As[base + 8192 + (arow + 64 + i * 16) * 32 + swz];
#pragma unroll
        for (int i = 0; i < 4; ++i)
#pragma unroll
            for (int j = 0; j < 4; ++j)
                acc[i][j] = __builtin_amdgcn_mfma_f32_16x16x32_bf16(a2[i], bB[j], acc[i][j], 0, 0, 0);
        __builtin_amdgcn_s_setprio(0);
        if (sA) { if (sB) vwait<12>(); else vwait<10>(); }
        SBAR;
        // ---- ph4: MFMA mh1/kk1 (a3,bB); prefetch next a0; gather B(kt+1,k0) ----
        if (sA) gatherB(bA, kt + 1, 0);
        SCHED0;
        __builtin_amdgcn_s_setprio(1);
        if (sA) {
            const int nb = (cur ^ 1) * 16384;
#pragma unroll
            for (int i = 0; i < 4; ++i)
                a0[i] = *(const bf16x8*)&As[nb + (arow + i * 16) * 32 + swz];
        }
#pragma unroll
        for (int i = 0; i < 4; ++i)
#pragma unroll
            for (int j = 0; j < 4; ++j)
                acc[4 + i][j] = __builtin_amdgcn_mfma_f32_16x16x32_bf16(a3[i], bB[j], acc[4 + i][j], 0, 0, 0);
        __builtin_amdgcn_s_setprio(0);
        SBAR;
    }
}

#define ACC_INIT8                                           \
    floatx4 acc[8][4];                                      \
    _Pragma("unroll") for (int i = 0; i < 8; ++i)           \
        _Pragma("unroll") for (int j = 0; j < 4; ++j)       \
            acc[i][j] = (floatx4){0.f, 0.f, 0.f, 0.f};

// ---------------------------------------------------------------------------
// legacy 128x128xBK=32 mainloop (k_dstWr fp32-staging path; k_dvalW2 pattern)
// ---------------------------------------------------------------------------
template <int AF32, int BF32>
__device__ inline void mainloop(unsigned short* As, unsigned short* Bs,
                                const void* Ap, size_t lda,
                                const void* Bp, size_t ldb,
                                int kIters, floatx4 (&acc)[4][4]) {
    const int t = threadIdx.x, lane = t & 63, wave = t >> 6;
    const int rA = t >> 2;
    const int cA = ((t & 3) ^ ((t >> 3) & 3)) * 8;      // swizzled source col
    const int mrow = (wave >> 1) * 64, ncol = (wave & 1) * 64;
    const int fr = lane & 15, fk = (lane >> 4) * 8;
    const int swz = (((fk >> 3) ^ ((fr >> 1) & 3)) << 3); // physical k-offset

    const unsigned short* gA16 = nullptr; const float* gA32 = nullptr;
    const unsigned short* gB16 = nullptr; const float* gB32 = nullptr;
    if (AF32) gA32 = (const float*)Ap + (size_t)rA * lda + cA;
    else      gA16 = (const unsigned short*)Ap + (size_t)rA * lda + cA;
    if (BF32) gB32 = (const float*)Bp + (size_t)rA * ldb + cA;
    else      gB16 = (const unsigned short*)Bp + (size_t)rA * ldb + cA;

    unsigned short* ldsA = As + wave * 512;
    unsigned short* ldsB = Bs + wave * 512;

    auto stage = [&](int buf) {
        const int o = buf * 4096;
        if (AF32) {
            *(uint4*)&As[o + t * 8]        = cvt8(gA32);
            *(uint4*)&As[o + 2048 + t * 8] = cvt8(gA32 + 64 * lda);
            gA32 += 32;
        } else {
            async16(ldsA + o,        gA16);
            async16(ldsA + o + 2048, gA16 + 64 * lda);
            gA16 += 32;
        }
        if (BF32) {
            *(uint4*)&Bs[o + t * 8]        = cvt8(gB32);
            *(uint4*)&Bs[o + 2048 + t * 8] = cvt8(gB32 + 64 * ldb);
            gB32 += 32;
        } else {
            async16(ldsB + o,        gB16);
            async16(ldsB + o + 2048, gB16 + 64 * ldb);
            gB16 += 32;
        }
    };

    stage(0);
    __syncthreads();
    for (int kt = 0; kt < kIters; ++kt) {
        if (kt + 1 < kIters) stage((kt + 1) & 1);
        const int cur = (kt & 1) * 4096;
        bf16x8 af[4], bfr[4];
#pragma unroll
        for (int i = 0; i < 4; ++i)
            af[i] = *(const bf16x8*)&As[cur + (mrow + i * 16 + fr) * 32 + swz];
#pragma unroll
        for (int j = 0; j < 4; ++j)
            bfr[j] = *(const bf16x8*)&Bs[cur + (ncol + j * 16 + fr) * 32 + swz];
#pragma unroll
        for (int i = 0; i < 4; ++i)
#pragma unroll
            for (int j = 0; j < 4; ++j)
                acc[i][j] = __builtin_amdgcn_mfma_f32_16x16x32_bf16(af[i], bfr[j],
                                                                    acc[i][j], 0, 0, 0);
        __syncthreads();
    }
}

#define EPILOGUE_COORDS                                     \
    const int lane = threadIdx.x & 63, wave = threadIdx.x >> 6; \
    const int mrow = (wave >> 1) * 64, ncol = (wave & 1) * 64;  \
    const int col = lane & 15, q = lane >> 4;

#define ACC_INIT                                            \
    floatx4 acc[4][4];                                      \
    _Pragma("unroll") for (int i = 0; i < 4; ++i)           \
        _Pragma("unroll") for (int j = 0; j < 4; ++j)       \
            acc[i][j] = (floatx4){0.f, 0.f, 0.f, 0.f};

// ---------------------------------------------------------------------------
// k_prep: srcb = bf16(src)   (LDS-free, 8 blocks/CU streaming)
// ---------------------------------------------------------------------------
__global__ __launch_bounds__(256) void k_prep(const float* __restrict__ src,
                                              unsigned short* __restrict__ srcb) {
    const size_t idx = ((size_t)blockIdx.x * 256 + threadIdx.x) * 8;
    *(uint4*)&srcb[idx] = cvt8(src + idx);
}

// ---------------------------------------------------------------------------
// k_dstWr: DW[b*dd][d] = SCALE * sum_e dst[b*dd][e] * Wr[d][e]   (128² loop)
// ---------------------------------------------------------------------------
__global__ __launch_bounds__(256) void k_dstWr(const float* __restrict__ dst,
                                               const float* __restrict__ Wr,
                                               unsigned short* __restrict__ DW) {
    __shared__ unsigned short As[2 * 128 * 32];
    __shared__ unsigned short Bs[2 * 128 * 32];
    const int n0 = blockIdx.x * 128, m0 = blockIdx.y * 128;
    ACC_INIT
    mainloop<1, 1>(As, Bs, dst + (size_t)m0 * DIM_, DIM_,
                   Wr + (size_t)n0 * DIM_, DIM_, DIM_ / 32, acc);
    EPILOGUE_COORDS
#pragma unroll
    for (int i = 0; i < 4; ++i)
#pragma unroll
        for (int j = 0; j < 4; ++j)
#pragma unroll
            for (int r = 0; r < 4; ++r)
                DW[(size_t)(m0 + mrow + i * 16 + q * 4 + r) * DIM_ +
                   n0 + ncol + j * 16 + col] = f2bf(acc[i][j][r] * SCALE);
}

// ---------------------------------------------------------------------------
// k_logitsT: LT[dd][s] = exp(DW[dd][:] . srcb[s][:]) -> bf16  (per batch)
// B-direct mainloop: srcb panel read natural-layout straight to B-frags.
// ---------------------------------------------------------------------------
__global__ __launch_bounds__(512, 2) void k_logitsT(const unsigned short* __restrict__ DW,
                                                    const unsigned short* __restrict__ srcb,
                                                    unsigned short* __restrict__ LTb,
                                                    float* __restrict__ Lpart) {
    __shared__ __align__(16) unsigned short As[32768];
    const int n = blockIdx.x;
    const int b = n & 7;          // -> XCD
    const int rem = n >> 3;       // [0,64)
    const int xs = rem >> 2;      // s-tile [0,16), slow (B L2-hot)
    const int yd = rem & 3;       // dd-tile [0,4)
    const int n0 = xs * 256, m0 = yd * 256;
    ACC_INIT8
    mainloop256(As,
                DW + (size_t)b * DD_ * DIM_ + (size_t)m0 * DIM_, DIM_,
                srcb + (size_t)b * S_ * DIM_ + (size_t)n0 * DIM_, DIM_,
                DIM_ / 64, acc);
    const int t = threadIdx.x, lane = t & 63, w = t >> 6;
    const int wm = w >> 2, wn = w & 3;
    const int c16 = lane & 15, q = lane >> 4;
    const int row0 = m0 + wm * 128, col0 = n0 + wn * 64;
    unsigned short* LT = LTb + (size_t)b * DD_ * S_;
    float psum[4] = {0.f, 0.f, 0.f, 0.f};
#pragma unroll
    for (int i = 0; i < 8; ++i)
#pragma unroll
        for (int j = 0; j < 4; ++j)
#pragma unroll
            for (int r = 0; r < 4; ++r) {
                float e = __expf(acc[i][j][r]);
                LT[(size_t)(row0 + i * 16 + q * 4 + r) * S_ +
                   col0 + j * 16 + c16] = f2bf(e);
                psum[j] += e;
            }
    float* csum = (float*)As;     // [8][256] overlay (buffer dead, drained)
    const int slice = wm * 4 + q;
#pragma unroll
    for (int j = 0; j < 4; ++j)
        csum[slice * 256 + wn * 64 + j * 16 + c16] = psum[j];
    __syncthreads();
    if (t < 256) {
        float v = 0.f;
#pragma unroll
        for (int k = 0; k < 8; ++k) v += csum[k * 256 + t];
        Lpart[((size_t)b * 4 + yd) * S_ + n0 + t] = v;
    }
}

// ---------------------------------------------------------------------------
// k_finalize: scale[b][s] = softplus(state)/denom; w[b][s] = scale*state
// ---------------------------------------------------------------------------
__global__ __launch_bounds__(256) void k_finalize(const float* __restrict__ state,
                                                  const float* __restrict__ Lpart,
                                                  float* __restrict__ scale,
                                                  float* __restrict__ w) {
    const int i = blockIdx.x * 256 + threadIdx.x;    // flat b*S+s
    const int b = i >> 12, s = i & (S_ - 1);
    float d = 0.f;
#pragma unroll
    for (int k = 0; k < 4; ++k) d += Lpart[((size_t)b * 4 + k) * S_ + s];
    const float st = state[i];
    const float sp = (st > 15.f) ? st : log1pf(__expf(st));
    const float sc = sp / d;
    scale[i] = sc;
    w[i] = sc * st;
}

// ---------------------------------------------------------------------------
// k_mid: blocks [0,2048): delta_state[b][dd] = sum_s LT[dd][s]*w[b][s]
//        blocks [2048,6144): srcST[b][d'][s] = bf16(scale[b][s]*srcb[b][s][d'])
// ---------------------------------------------------------------------------
__global__ __launch_bounds__(256) void k_mid(const unsigned short* __restrict__ LTb,
                                             const float* __restrict__ w,
                                             const unsigned short* __restrict__ srcb,
                                             const float* __restrict__ scale,
                                             unsigned short* __restrict__ srcST,
                                             float* __restrict__ out) {
    __shared__ unsigned short Ts[64 * 65];
    const int bx = blockIdx.x;
    const int t = threadIdx.x;
    if (bx < 2048) {   // ---- dstate ----
        const int b = bx >> 8;
        const int dd = (bx & 255) * 4 + (t >> 6);
        const int lane = t & 63;
        const unsigned short* row = LTb + (size_t)b * DD_ * S_ + (size_t)dd * S_;
        const float* wp = w + (size_t)b * S_;
        float acc = 0.f;
#pragma unroll
        for (int it = 0; it < S_ / 512; ++it) {
            const int s = it * 512 + lane * 8;
            uint4 v = *(const uint4*)(row + s);
            const unsigned short* e = (const unsigned short*)&v;
            float4 w0 = *(const float4*)(wp + s);
            float4 w1 = *(const float4*)(wp + s + 4);
            acc += bf2f(e[0]) * w0.x + bf2f(e[1]) * w0.y +
                   bf2f(e[2]) * w0.z + bf2f(e[3]) * w0.w +
                   bf2f(e[4]) * w1.x + bf2f(e[5]) * w1.y +
                   bf2f(e[6]) * w1.z + bf2f(e[7]) * w1.w;
        }
#pragma unroll
        for (int off = 32; off; off >>= 1) acc += __shfl_down(acc, off);
        if (lane == 0) out[(size_t)b * DD_ + dd] = acc;
        return;
    }
    // ---- srcT ----
    const int i2 = bx - 2048;
    const int s0 = (i2 & 63) * 64, d0 = ((i2 >> 6) & 7) * 64, b = i2 >> 9;
    {
        const int r = t >> 2, c0 = (t & 3) * 16;   // r = s-local, c = d'-local
        const unsigned short* g =
            srcb + (size_t)b * S_ * DIM_ + (size_t)(s0 + r) * DIM_ + d0 + c0;
        uint4 v0 = *(const uint4*)g;
        uint4 v1 = *(const uint4*)(g + 8);
        const unsigned short* e0 = (const unsigned short*)&v0;
        const unsigned short* e1 = (const unsigned short*)&v1;
        const float sc = scale[(size_t)b * S_ + s0 + r];
#pragma unroll
        for (int i = 0; i < 8; ++i) {
            Ts[r * 65 + c0 + i]     = f2bf(bf2f(e0[i]) * sc);
            Ts[r * 65 + c0 + 8 + i] = f2bf(bf2f(e1[i]) * sc);
        }
    }
    __syncthreads();
    {
        const int rr = t >> 2, c0 = (t & 3) * 16;  // rr = d'-local, c = s-local
        unsigned short tmp[16];
#pragma unroll
        for (int j = 0; j < 16; ++j) tmp[j] = Ts[(c0 + j) * 65 + rr];
        unsigned short* o =
            srcST + (size_t)b * DIM_ * S_ + (size_t)(d0 + rr) * S_ + s0 + c0;
        *(uint4*)o = *(const uint4*)tmp;
        *(uint4*)(o + 8) = *(const uint4*)(tmp + 8);
    }
}

// ---------------------------------------------------------------------------
// k_dU: partial[ks][b][dd][d'] = sum_{s slice} LT[dd][s]*srcST[d'][s], fp16
// B-direct mainloop: srcST panel read natural-layout straight to B-frags.
// ---------------------------------------------------------------------------
__global__ __launch_bounds__(512, 2) void k_dU(const unsigned short* __restrict__ LTb,
                                               const unsigned short* __restrict__ srcST,
                                               __half* __restrict__ Pp) {
    __shared__ __align__(16) unsigned short As[32768];
    const int n = blockIdx.x;                 // [0,256)
    const int qn = n >> 3;                    // [0,32)
    const int tile = qn & 7, zhi = qn >> 3;   // tile [0,8), zhi [0,4)
    const int z = (n & 7) + 8 * zhi;          // (b,ks) [0,32); XCD = n&7 = z&7
    const int b = z >> 2, ks = z & 3;
    const int xe = tile >> 2;                 // d'-tile [0,2)
    const int yd = tile & 3;                  // dd-tile [0,4)
    const int n0 = xe * 256, m0 = yd * 256;
    ACC_INIT8
    mainloop256(As,
                LTb + (size_t)b * DD_ * S_ + (size_t)m0 * S_ + ks * 1024, S_,
                srcST + (size_t)b * DIM_ * S_ + (size_t)n0 * S_ + ks * 1024, S_,
                1024 / 64, acc);
    const int t = threadIdx.x, lane = t & 63, w = t >> 6;
    const int wm = w >> 2, wn = w & 3;
    const int c16 = lane & 15, q = lane >> 4;
    const int row0 = m0 + wm * 128, col0 = n0 + wn * 64;
    __half* O = Pp + (size_t)ks * PPN + (size_t)b * DD_ * DIM_;
#pragma unroll
    for (int i = 0; i < 8; ++i)
#pragma unroll
        for (int j = 0; j < 4; ++j)
#pragma unroll
            for (int r = 0; r < 4; ++r)
                O[(size_t)(row0 + i * 16 + q * 4 + r) * DIM_ +
                  col0 + j * 16 + c16] = __float2half(acc[i][j][r]);
}

// ---------------------------------------------------------------------------
// k_dvalW2: d_val[b*dd][e] = sum_d' (Σks Pp[ks][b*dd][d']) * Wv[d'][e]
// (absorbs reduceU; A = fp32-sum of 4 fp16 Pp slices -> f2bf, identical value
// chain; Wv transposed in-kernel with conflict-free packed b32 writes.)
// ---------------------------------------------------------------------------
__global__ __launch_bounds__(256) void k_dvalW2(const __half* __restrict__ Pp,
                                                const float* __restrict__ Wv,
                                                float* __restrict__ d_val) {
    __shared__ unsigned short As[2 * 128 * 32];
    __shared__ unsigned short Bs[2 * 128 * 32];
    const int n0 = blockIdx.x * 128, m0 = blockIdx.y * 128;
    const int t = threadIdx.x;
    const int rA = t >> 2, cA = ((t & 3) ^ ((t >> 3) & 3)) * 8;
    const __half* gA = Pp + (size_t)(m0 + rA) * DIM_ + cA;
    const int d0 = (t >> 4) * 2;      // [0,32) step 2 (K-local)
    const int ecol = t & 15;          // e = ecol + 16*i

    ACC_INIT
    auto stageA8 = [&](unsigned short* dst, const __half* g) {
        float o[8] = {0.f, 0.f, 0.f, 0.f, 0.f, 0.f, 0.f, 0.f};
#pragma unroll
        for (int ksl = 0; ksl < 4; ++ksl) {
            uint4 v = *(const uint4*)(g + (size_t)ksl * PPN);
            const __half* h = (const __half*)&v;
#pragma unroll
            for (int j = 0; j < 8; ++j) o[j] += __half2float(h[j]);
        }
        unsigned short tmp[8];
#pragma unroll
        for (int j = 0; j < 8; ++j) tmp[j] = f2bf(o[j]);
        *(uint4*)dst = *(const uint4*)tmp;
    };
    auto stage = [&](int buf, int kt) {
        const int o = buf * 4096;
        stageA8(&As[o + t * 8],        gA + kt * 32);
        stageA8(&As[o + 2048 + t * 8], gA + kt * 32 + (size_t)64 * DIM_);
        const float* wv = Wv + (size_t)(kt * 32 + d0) * DIM_ + n0 + ecol;
#pragma unroll
        for (int i = 0; i < 8; ++i) {
            float v0 = wv[16 * i];
            float v1 = wv[16 * i + DIM_];
            unsigned int pk = (unsigned int)f2bf(v0) | ((unsigned int)f2bf(v1) << 16);
            const int e = ecol + 16 * i;
            const int phys = e * 32 + (((d0 >> 3) ^ ((e >> 1) & 3)) << 3) + (d0 & 7);
            *(unsigned int*)&Bs[o + phys] = pk;
        }
    };

    stage(0, 0);
    __syncthreads();
    const int lane = t & 63, wave = t >> 6;
    const int mrow = (wave >> 1) * 64, ncol = (wave & 1) * 64;
    const int fr = lane & 15, fk = (lane >> 4) * 8;
    const int swz = (((fk >> 3) ^ ((fr >> 1) & 3)) << 3);
    for (int kt = 0; kt < DIM_ / 32; ++kt) {
        if (kt + 1 < DIM_ / 32) stage((kt + 1) & 1, kt + 1);
        const int cur = (kt & 1) * 4096;
        bf16x8 af[4], bfr[4];
#pragma unroll
        for (int i = 0; i < 4; ++i)
            af[i] = *(const bf16x8*)&As[cur + (mrow + i * 16 + fr) * 32 + swz];
#pragma unroll
        for (int j = 0; j < 4; ++j)
            bfr[j] = *(const bf16x8*)&Bs[cur + (ncol + j * 16 + fr) * 32 + swz];
#pragma unroll
        for (int i = 0; i < 4; ++i)
#pragma unroll
            for (int j = 0; j < 4; ++j)
                acc[i][j] = __builtin_amdgcn_mfma_f32_16x16x32_bf16(af[i], bfr[j],
                                                                    acc[i][j], 0, 0, 0);
        __syncthreads();
    }
    const int col = lane & 15, q = lane >> 4;
#pragma unroll
    for (int i = 0; i < 4; ++i)
#pragma unroll
        for (int j = 0; j < 4; ++j)
#pragma unroll
            for (int r = 0; r < 4; ++r)
                d_val[(size_t)(m0 + mrow + i * 16 + q * 4 + r) * DIM_ +
                      n0 + ncol + j * 16 + col] = acc[i][j][r];
}

// ---------------------------------------------------------------------------
extern "C" void kernel_launch(void* const* d_in, const int* in_sizes, int n_in,
                              void* d_out, int out_size, void* d_ws, size_t ws_size,
                              hipStream_t stream) {
    const float* src   = (const float*)d_in[0];   // [B,S,DIM]
    const float* state = (const float*)d_in[1];   // [B,S]
    const float* dst   = (const float*)d_in[2];   // [B,D,DIM]
    const float* Wr    = (const float*)d_in[3];   // [DIM,DIM]
    const float* Wv    = (const float*)d_in[4];   // [DIM,DIM]

    // ws layout (128 MiB):
    //  A [0,32):  srcb bf16 (prep -> mid); late: Pp fp16 4x8MiB (dU -> dvalW2)
    //  B [32,96): LT bf16 (logitsT -> dU, mid)
    //  C [96,128): early: DW(8MB) + Lpart(.5MB); late: srcST (32MB, mid -> dU)
    //  scale & w park in d_out's d_val region (dead until k_dvalW2 writes it)
    unsigned short* srcb = (unsigned short*)d_ws;
    __half* Pp = (__half*)d_ws;                                // overlays dead srcb
    unsigned short* LT = srcb + (size_t)B_ * S_ * DIM_;
    unsigned short* C = LT + (size_t)B_ * DD_ * S_;
    unsigned short* DW = C;
    float* Lpart = (float*)(DW + (size_t)B_ * DD_ * DIM_);     // [B][4][S]
    unsigned short* srcST = C;                                 // overlays dead DW/Lpart

    float* d_state = (float*)d_out;               // [B, DD]
    float* d_val   = (float*)d_out + B_ * DD_;    // [B, DD, DIM]
    float* scale   = d_val;                       // park (dead before k_dvalW2)
    float* w       = d_val + (size_t)B_ * S_;     // park, right after scale

    k_prep<<<dim3(8192), 256, 0, stream>>>(src, srcb);
    k_dstWr<<<dim3(DIM_ / 128, (B_ * DD_) / 128), 256, 0, stream>>>(dst, Wr, DW);
    k_logitsT<<<dim3(512), 512, 0, stream>>>(DW, srcb, LT, Lpart);
    k_finalize<<<dim3((B_ * S_) / 256), 256, 0, stream>>>(state, Lpart, scale, w);
    k_mid<<<dim3(2048 + 4096), 256, 0, stream>>>(LT, w, srcb, scale, srcST, d_state);
    k_dU<<<dim3(256), 512, 0, stream>>>(LT, srcST, Pp);
    k_dvalW2<<<dim3(DIM_ / 128, (B_ * DD_) / 128), 256, 0, stream>>>(Pp, Wv, d_val);
}

// Round 8
// 281.481 us; speedup vs baseline: 1.1206x; 1.1206x over previous
//
#include <hip/hip_runtime.h>
#include <hip/hip_fp16.h>

#define B_   8
#define S_   4096
#define DD_  1024   // dst nodes
#define DIM_ 512
#define SCALE 0.044194173824159216f  // 1/sqrt(512)
#define PPN  ((size_t)B_ * DD_ * DIM_)   // Pp slice stride (halfwords/elems)

typedef __bf16 bf16x8 __attribute__((ext_vector_type(8)));
typedef float  floatx4 __attribute__((ext_vector_type(4)));

__device__ inline unsigned short f2bf(float f) {
    union { float f; unsigned int u; } v; v.f = f;
    unsigned int r = v.u + 0x7fffu + ((v.u >> 16) & 1u);  // RNE
    return (unsigned short)(r >> 16);
}
__device__ inline float bf2f(unsigned short h) {
    union { unsigned int u; float f; } v; v.u = ((unsigned int)h) << 16;
    return v.f;
}
__device__ inline uint4 cvt8(const float* __restrict__ g) {
    float4 f0 = *(const float4*)g;
    float4 f1 = *(const float4*)(g + 4);
    unsigned short tmp[8] = {f2bf(f0.x), f2bf(f0.y), f2bf(f0.z), f2bf(f0.w),
                             f2bf(f1.x), f2bf(f1.y), f2bf(f1.z), f2bf(f1.w)};
    return *(const uint4*)tmp;
}
// async global->LDS, 16B per lane; lds base must be wave-uniform
__device__ inline void async16(unsigned short* lds, const unsigned short* g) {
    __builtin_amdgcn_global_load_lds(
        (const __attribute__((address_space(1))) void*)g,
        (__attribute__((address_space(3))) void*)lds, 16, 0, 0);
}

template <int N> __device__ inline void vwait() {
    if constexpr (N == 0)      asm volatile("s_waitcnt vmcnt(0)" ::: "memory");
    else if constexpr (N == 4) asm volatile("s_waitcnt vmcnt(4)" ::: "memory");
    else if constexpr (N == 6) asm volatile("s_waitcnt vmcnt(6)" ::: "memory");
    else                       asm volatile("s_waitcnt vmcnt(8)" ::: "memory");
}
#define SBAR   __builtin_amdgcn_s_barrier()
#define SCHED0 __builtin_amdgcn_sched_barrier(0)

// ===========================================================================
// 256x256xK fully-pipelined mainloop (R4-proven; R7's B-direct variant
// REVERTED: mixing register B-gathers into the counted-vmcnt stream forces
// the compiler to drain vmcnt to ~2 before each B-consuming MFMA, killing
// the 12-deep A/B pipeline — measured 63.5 µs vs 48.6 µs, MfmaUtil 20%).
// BK=64, 512 threads = 8 waves (2M x 4N), per-wave output 128x64 (acc[8][4]).
// LDS per operand: [2 buf][2 khalf][256][32] bf16 = 64 KiB; 128 KiB total.
// 4 phases/K-tile, one barrier/phase; each phase's ds_reads issued one phase
// early inside the previous phase's MFMA cluster; counted vmcnt 6/4/0 peel.
// Swizzle: phys 16B slot = logical ^ ((row>>1)&3); inverse perm on global
// source (LDS dest linear for global_load_lds), per-lane-const XOR on read.
// acc[8][4]=128 AGPR + 112 VGPR -> hard 2 waves/SIMD, 1 block/CU.
// ===========================================================================
__device__ inline void mainloop256(unsigned short* As, unsigned short* Bs,
                                   const unsigned short* __restrict__ Ap, size_t lda,
                                   const unsigned short* __restrict__ Bp, size_t ldb,
                                   int nk, floatx4 (&acc)[8][4]) {
    const int t = threadIdx.x, lane = t & 63, w = t >> 6;
    const int wm = w >> 2, wn = w & 3;
    const int fr = lane & 15;
    const int swz  = (((lane >> 4) ^ ((fr >> 1) & 3)) << 3);   // read-side slot XOR
    const int csrc = (((t & 3) ^ ((t >> 3) & 3)) << 3);        // source-side inverse

    const unsigned short* gA = Ap + (size_t)(t >> 2) * lda + csrc;
    const unsigned short* gB = Bp + (size_t)(t >> 2) * ldb + csrc;
    unsigned short* ldsA = As + w * 512;   // wave-uniform; +lane*16B implicit
    unsigned short* ldsB = Bs + w * 512;

    auto stgA = [&](int buf, int kt, int kh) {
        const unsigned short* g = gA + (size_t)kt * 64 + kh * 32;
        async16(ldsA + buf * 16384 + kh * 8192,        g);
        async16(ldsA + buf * 16384 + kh * 8192 + 4096, g + (size_t)128 * lda);
    };
    auto stgB = [&](int buf, int kt, int kh) {
        const unsigned short* g = gB + (size_t)kt * 64 + kh * 32;
        async16(ldsB + buf * 16384 + kh * 8192,        g);
        async16(ldsB + buf * 16384 + kh * 8192 + 4096, g + (size_t)128 * ldb);
    };

    // prologue: tile0 (kk0,kk1) + tile1 kk0 = 12 loads in flight
    stgA(0, 0, 0); stgB(0, 0, 0); stgA(0, 0, 1); stgB(0, 0, 1);
    stgA(1, 1, 0); stgB(1, 1, 0);
    vwait<8>();                     // tile0 kk0 resident
    SCHED0;
    SBAR;

    const int arow = wm * 128 + fr, brow = wn * 64 + fr;
    bf16x8 a0[4], b0[4], a1[4], a2[4], b2[4], a3[4];
#pragma unroll
    for (int i = 0; i < 4; ++i) a0[i] = *(const bf16x8*)&As[(arow + i * 16) * 32 + swz];
#pragma unroll
    for (int j = 0; j < 4; ++j) b0[j] = *(const bf16x8*)&Bs[(brow + j * 16) * 32 + swz];

    for (int kt = 0; kt < nk; ++kt) {
        const int cur = kt & 1, base = cur * 16384;
        const bool sA = kt + 1 < nk, sB = kt + 2 < nk;
        // ---- ph1: MFMA mh0/kk0; prefetch a1 (mh1/kk0); stage A(kt+1,k1) ----
        if (sA) stgA(cur ^ 1, kt + 1, 1);
        SCHED0;
        __builtin_amdgcn_s_setprio(1);
#pragma unroll
        for (int i = 0; i < 4; ++i)
            a1[i] = *(const bf16x8*)&As[base + (arow + 64 + i * 16) * 32 + swz];
#pragma unroll
        for (int i = 0; i < 4; ++i)
#pragma unroll
            for (int j = 0; j < 4; ++j)
                acc[i][j] = __builtin_amdgcn_mfma_f32_16x16x32_bf16(a0[i], b0[j], acc[i][j], 0, 0, 0);
        __builtin_amdgcn_s_setprio(0);
        if (sA) vwait<6>(); else vwait<0>();   // this tile's kk1 resident
        SBAR;
        // ---- ph2: MFMA mh1/kk0; prefetch a2,b2 (kk1); stage B(kt+1,k1) ----
        if (sA) stgB(cur ^ 1, kt + 1, 1);
        SCHED0;
        __builtin_amdgcn_s_setprio(1);
#pragma unroll
        for (int i = 0; i < 4; ++i)
            a2[i] = *(const bf16x8*)&As[base + 8192 + (arow + i * 16) * 32 + swz];
#pragma unroll
        for (int j = 0; j < 4; ++j)
            b2[j] = *(const bf16x8*)&Bs[base + 8192 + (brow + j * 16) * 32 + swz];
#pragma unroll
        for (int i = 0; i < 4; ++i)
#pragma unroll
            for (int j = 0; j < 4; ++j)
                acc[4 + i][j] = __builtin_amdgcn_mfma_f32_16x16x32_bf16(a1[i], b0[j], acc[4 + i][j], 0, 0, 0);
        __builtin_amdgcn_s_setprio(0);
        SBAR;
        // ---- ph3: MFMA mh0/kk1; prefetch a3 (mh1/kk1); stage A(kt+2,k0) ----
        if (sB) stgA(cur, kt + 2, 0);
        SCHED0;
        __builtin_amdgcn_s_setprio(1);
#pragma unroll
        for (int i = 0; i < 4; ++i)
            a3[i] = *(const bf16x8*)&As[base + 8192 + (arow + 64 + i * 16) * 32 + swz];
#pragma unroll
        for (int i = 0; i < 4; ++i)
#pragma unroll
            for (int j = 0; j < 4; ++j)
                acc[i][j] = __builtin_amdgcn_mfma_f32_16x16x32_bf16(a2[i], b2[j], acc[i][j], 0, 0, 0);
        __builtin_amdgcn_s_setprio(0);
        if (sA) { if (sB) vwait<6>(); else vwait<4>(); }  // next tile kk0 resident
        SBAR;
        // ---- ph4: MFMA mh1/kk1; prefetch next a0,b0 (kk0); stage B(kt+2,k0) ----
        if (sB) stgB(cur, kt + 2, 0);
        SCHED0;
        __builtin_amdgcn_s_setprio(1);
        if (sA) {
            const int nb = (cur ^ 1) * 16384;
#pragma unroll
            for (int i = 0; i < 4; ++i)
                a0[i] = *(const bf16x8*)&As[nb + (arow + i * 16) * 32 + swz];
#pragma unroll
            for (int j = 0; j < 4; ++j)
                b0[j] = *(const bf16x8*)&Bs[nb + (brow + j * 16) * 32 + swz];
        }
#pragma unroll
        for (int i = 0; i < 4; ++i)
#pragma unroll
            for (int j = 0; j < 4; ++j)
                acc[4 + i][j] = __builtin_amdgcn_mfma_f32_16x16x32_bf16(a3[i], b2[j], acc[4 + i][j], 0, 0, 0);
        __builtin_amdgcn_s_setprio(0);
        SBAR;
    }
}

#define ACC_INIT8                                           \
    floatx4 acc[8][4];                                      \
    _Pragma("unroll") for (int i = 0; i < 8; ++i)           \
        _Pragma("unroll") for (int j = 0; j < 4; ++j)       \
            acc[i][j] = (floatx4){0.f, 0.f, 0.f, 0.f};

// ---------------------------------------------------------------------------
// legacy 128x128xBK=32 mainloop (k_dstWr fp32-staging path)
// ---------------------------------------------------------------------------
template <int AF32, int BF32>
__device__ inline void mainloop(unsigned short* As, unsigned short* Bs,
                                const void* Ap, size_t lda,
                                const void* Bp, size_t ldb,
                                int kIters, floatx4 (&acc)[4][4]) {
    const int t = threadIdx.x, lane = t & 63, wave = t >> 6;
    const int rA = t >> 2;
    const int cA = ((t & 3) ^ ((t >> 3) & 3)) * 8;      // swizzled source col
    const int mrow = (wave >> 1) * 64, ncol = (wave & 1) * 64;
    const int fr = lane & 15, fk = (lane >> 4) * 8;
    const int swz = (((fk >> 3) ^ ((fr >> 1) & 3)) << 3); // physical k-offset

    const unsigned short* gA16 = nullptr; const float* gA32 = nullptr;
    const unsigned short* gB16 = nullptr; const float* gB32 = nullptr;
    if (AF32) gA32 = (const float*)Ap + (size_t)rA * lda + cA;
    else      gA16 = (const unsigned short*)Ap + (size_t)rA * lda + cA;
    if (BF32) gB32 = (const float*)Bp + (size_t)rA * ldb + cA;
    else      gB16 = (const unsigned short*)Bp + (size_t)rA * ldb + cA;

    unsigned short* ldsA = As + wave * 512;
    unsigned short* ldsB = Bs + wave * 512;

    auto stage = [&](int buf) {
        const int o = buf * 4096;
        if (AF32) {
            *(uint4*)&As[o + t * 8]        = cvt8(gA32);
            *(uint4*)&As[o + 2048 + t * 8] = cvt8(gA32 + 64 * lda);
            gA32 += 32;
        } else {
            async16(ldsA + o,        gA16);
            async16(ldsA + o + 2048, gA16 + 64 * lda);
            gA16 += 32;
        }
        if (BF32) {
            *(uint4*)&Bs[o + t * 8]        = cvt8(gB32);
            *(uint4*)&Bs[o + 2048 + t * 8] = cvt8(gB32 + 64 * ldb);
            gB32 += 32;
        } else {
            async16(ldsB + o,        gB16);
            async16(ldsB + o + 2048, gB16 + 64 * ldb);
            gB16 += 32;
        }
    };

    stage(0);
    __syncthreads();
    for (int kt = 0; kt < kIters; ++kt) {
        if (kt + 1 < kIters) stage((kt + 1) & 1);
        const int cur = (kt & 1) * 4096;
        bf16x8 af[4], bfr[4];
#pragma unroll
        for (int i = 0; i < 4; ++i)
            af[i] = *(const bf16x8*)&As[cur + (mrow + i * 16 + fr) * 32 + swz];
#pragma unroll
        for (int j = 0; j < 4; ++j)
            bfr[j] = *(const bf16x8*)&Bs[cur + (ncol + j * 16 + fr) * 32 + swz];
#pragma unroll
        for (int i = 0; i < 4; ++i)
#pragma unroll
            for (int j = 0; j < 4; ++j)
                acc[i][j] = __builtin_amdgcn_mfma_f32_16x16x32_bf16(af[i], bfr[j],
                                                                    acc[i][j], 0, 0, 0);
        __syncthreads();
    }
}

#define EPILOGUE_COORDS                                     \
    const int lane = threadIdx.x & 63, wave = threadIdx.x >> 6; \
    const int mrow = (wave >> 1) * 64, ncol = (wave & 1) * 64;  \
    const int col = lane & 15, q = lane >> 4;

#define ACC_INIT                                            \
    floatx4 acc[4][4];                                      \
    _Pragma("unroll") for (int i = 0; i < 4; ++i)           \
        _Pragma("unroll") for (int j = 0; j < 4; ++j)       \
            acc[i][j] = (floatx4){0.f, 0.f, 0.f, 0.f};

// ---------------------------------------------------------------------------
// k_prep: srcb = bf16(src)   (LDS-free, 8 blocks/CU streaming)
// ---------------------------------------------------------------------------
__global__ __launch_bounds__(256) void k_prep(const float* __restrict__ src,
                                              unsigned short* __restrict__ srcb) {
    const size_t idx = ((size_t)blockIdx.x * 256 + threadIdx.x) * 8;
    *(uint4*)&srcb[idx] = cvt8(src + idx);
}

// ---------------------------------------------------------------------------
// k_dstWr: DW[b*dd][d] = SCALE * sum_e dst[b*dd][e] * Wr[d][e]   (128² loop)
// ---------------------------------------------------------------------------
__global__ __launch_bounds__(256) void k_dstWr(const float* __restrict__ dst,
                                               const float* __restrict__ Wr,
                                               unsigned short* __restrict__ DW) {
    __shared__ unsigned short As[2 * 128 * 32];
    __shared__ unsigned short Bs[2 * 128 * 32];
    const int n0 = blockIdx.x * 128, m0 = blockIdx.y * 128;
    ACC_INIT
    mainloop<1, 1>(As, Bs, dst + (size_t)m0 * DIM_, DIM_,
                   Wr + (size_t)n0 * DIM_, DIM_, DIM_ / 32, acc);
    EPILOGUE_COORDS
#pragma unroll
    for (int i = 0; i < 4; ++i)
#pragma unroll
        for (int j = 0; j < 4; ++j)
#pragma unroll
            for (int r = 0; r < 4; ++r)
                DW[(size_t)(m0 + mrow + i * 16 + q * 4 + r) * DIM_ +
                   n0 + ncol + j * 16 + col] = f2bf(acc[i][j][r] * SCALE);
}

// ---------------------------------------------------------------------------
// k_logitsT: LT[dd][s] = exp(DW[dd][:] . srcb[s][:]) -> bf16  (per batch)
// R4-proven mainloop (LDS-staged B). XCD: b = n&7; s-tile slow.
// ---------------------------------------------------------------------------
__global__ __launch_bounds__(512, 2) void k_logitsT(const unsigned short* __restrict__ DW,
                                                    const unsigned short* __restrict__ srcb,
                                                    unsigned short* __restrict__ LTb,
                                                    float* __restrict__ Lpart) {
    __shared__ __align__(16) unsigned short As[32768];
    __shared__ __align__(16) unsigned short Bs[32768];
    const int n = blockIdx.x;
    const int b = n & 7;          // -> XCD
    const int rem = n >> 3;       // [0,64)
    const int xs = rem >> 2;      // s-tile [0,16), slow (B L2-hot)
    const int yd = rem & 3;       // dd-tile [0,4)
    const int n0 = xs * 256, m0 = yd * 256;
    ACC_INIT8
    mainloop256(As, Bs,
                DW + (size_t)b * DD_ * DIM_ + (size_t)m0 * DIM_, DIM_,
                srcb + (size_t)b * S_ * DIM_ + (size_t)n0 * DIM_, DIM_,
                DIM_ / 64, acc);
    const int t = threadIdx.x, lane = t & 63, w = t >> 6;
    const int wm = w >> 2, wn = w & 3;
    const int c16 = lane & 15, q = lane >> 4;
    const int row0 = m0 + wm * 128, col0 = n0 + wn * 64;
    unsigned short* LT = LTb + (size_t)b * DD_ * S_;
    float psum[4] = {0.f, 0.f, 0.f, 0.f};
#pragma unroll
    for (int i = 0; i < 8; ++i)
#pragma unroll
        for (int j = 0; j < 4; ++j)
#pragma unroll
            for (int r = 0; r < 4; ++r) {
                float e = __expf(acc[i][j][r]);
                LT[(size_t)(row0 + i * 16 + q * 4 + r) * S_ +
                   col0 + j * 16 + c16] = f2bf(e);
                psum[j] += e;
            }
    float* csum = (float*)As;     // [8][256] overlay (buffers dead)
    const int slice = wm * 4 + q;
#pragma unroll
    for (int j = 0; j < 4; ++j)
        csum[slice * 256 + wn * 64 + j * 16 + c16] = psum[j];
    __syncthreads();
    if (t < 256) {
        float v = 0.f;
#pragma unroll
        for (int k = 0; k < 8; ++k) v += csum[k * 256 + t];
        Lpart[((size_t)b * 4 + yd) * S_ + n0 + t] = v;
    }
}

// ---------------------------------------------------------------------------
// k_finalize: scale[b][s] = softplus(state)/denom; w[b][s] = scale*state
// ---------------------------------------------------------------------------
__global__ __launch_bounds__(256) void k_finalize(const float* __restrict__ state,
                                                  const float* __restrict__ Lpart,
                                                  float* __restrict__ scale,
                                                  float* __restrict__ w) {
    const int i = blockIdx.x * 256 + threadIdx.x;    // flat b*S+s
    const int b = i >> 12, s = i & (S_ - 1);
    float d = 0.f;
#pragma unroll
    for (int k = 0; k < 4; ++k) d += Lpart[((size_t)b * 4 + k) * S_ + s];
    const float st = state[i];
    const float sp = (st > 15.f) ? st : log1pf(__expf(st));
    const float sc = sp / d;
    scale[i] = sc;
    w[i] = sc * st;
}

// ---------------------------------------------------------------------------
// k_mid: blocks [0,2048): delta_state[b][dd] = sum_s LT[dd][s]*w[b][s]
//        blocks [2048,6144): srcST[b][d'][s] = bf16(scale[b][s]*srcb[b][s][d'])
// ---------------------------------------------------------------------------
__global__ __launch_bounds__(256) void k_mid(const unsigned short* __restrict__ LTb,
                                             const float* __restrict__ w,
                                             const unsigned short* __restrict__ srcb,
                                             const float* __restrict__ scale,
                                             unsigned short* __restrict__ srcST,
                                             float* __restrict__ out) {
    __shared__ unsigned short Ts[64 * 65];
    const int bx = blockIdx.x;
    const int t = threadIdx.x;
    if (bx < 2048) {   // ---- dstate ----
        const int b = bx >> 8;
        const int dd = (bx & 255) * 4 + (t >> 6);
        const int lane = t & 63;
        const unsigned short* row = LTb + (size_t)b * DD_ * S_ + (size_t)dd * S_;
        const float* wp = w + (size_t)b * S_;
        float acc = 0.f;
#pragma unroll
        for (int it = 0; it < S_ / 512; ++it) {
            const int s = it * 512 + lane * 8;
            uint4 v = *(const uint4*)(row + s);
            const unsigned short* e = (const unsigned short*)&v;
            float4 w0 = *(const float4*)(wp + s);
            float4 w1 = *(const float4*)(wp + s + 4);
            acc += bf2f(e[0]) * w0.x + bf2f(e[1]) * w0.y +
                   bf2f(e[2]) * w0.z + bf2f(e[3]) * w0.w +
                   bf2f(e[4]) * w1.x + bf2f(e[5]) * w1.y +
                   bf2f(e[6]) * w1.z + bf2f(e[7]) * w1.w;
        }
#pragma unroll
        for (int off = 32; off; off >>= 1) acc += __shfl_down(acc, off);
        if (lane == 0) out[(size_t)b * DD_ + dd] = acc;
        return;
    }
    // ---- srcT ----
    const int i2 = bx - 2048;
    const int s0 = (i2 & 63) * 64, d0 = ((i2 >> 6) & 7) * 64, b = i2 >> 9;
    {
        const int r = t >> 2, c0 = (t & 3) * 16;   // r = s-local, c = d'-local
        const unsigned short* g =
            srcb + (size_t)b * S_ * DIM_ + (size_t)(s0 + r) * DIM_ + d0 + c0;
        uint4 v0 = *(const uint4*)g;
        uint4 v1 = *(const uint4*)(g + 8);
        const unsigned short* e0 = (const unsigned short*)&v0;
        const unsigned short* e1 = (const unsigned short*)&v1;
        const float sc = scale[(size_t)b * S_ + s0 + r];
#pragma unroll
        for (int i = 0; i < 8; ++i) {
            Ts[r * 65 + c0 + i]     = f2bf(bf2f(e0[i]) * sc);
            Ts[r * 65 + c0 + 8 + i] = f2bf(bf2f(e1[i]) * sc);
        }
    }
    __syncthreads();
    {
        const int rr = t >> 2, c0 = (t & 3) * 16;  // rr = d'-local, c = s-local
        unsigned short tmp[16];
#pragma unroll
        for (int j = 0; j < 16; ++j) tmp[j] = Ts[(c0 + j) * 65 + rr];
        unsigned short* o =
            srcST + (size_t)b * DIM_ * S_ + (size_t)(d0 + rr) * S_ + s0 + c0;
        *(uint4*)o = *(const uint4*)tmp;
        *(uint4*)(o + 8) = *(const uint4*)(tmp + 8);
    }
}

// ---------------------------------------------------------------------------
// k_dU: partial[ks][b][dd][d'] = sum_{s slice} LT[dd][s]*srcST[d'][s], fp16
// R4-proven mainloop; split-K=4; all 8 tiles of one (b,ks) on one XCD.
// ---------------------------------------------------------------------------
__global__ __launch_bounds__(512, 2) void k_dU(const unsigned short* __restrict__ LTb,
                                               const unsigned short* __restrict__ srcST,
                                               __half* __restrict__ Pp) {
    __shared__ __align__(16) unsigned short As[32768];
    __shared__ __align__(16) unsigned short Bs[32768];
    const int n = blockIdx.x;                 // [0,256)
    const int qn = n >> 3;                    // [0,32)
    const int tile = qn & 7, zhi = qn >> 3;   // tile [0,8), zhi [0,4)
    const int z = (n & 7) + 8 * zhi;          // (b,ks) [0,32); XCD = n&7 = z&7
    const int b = z >> 2, ks = z & 3;
    const int xe = tile >> 2;                 // d'-tile [0,2)
    const int yd = tile & 3;                  // dd-tile [0,4)
    const int n0 = xe * 256, m0 = yd * 256;
    ACC_INIT8
    mainloop256(As, Bs,
                LTb + (size_t)b * DD_ * S_ + (size_t)m0 * S_ + ks * 1024, S_,
                srcST + (size_t)b * DIM_ * S_ + (size_t)n0 * S_ + ks * 1024, S_,
                1024 / 64, acc);
    const int t = threadIdx.x, lane = t & 63, w = t >> 6;
    const int wm = w >> 2, wn = w & 3;
    const int c16 = lane & 15, q = lane >> 4;
    const int row0 = m0 + wm * 128, col0 = n0 + wn * 64;
    __half* O = Pp + (size_t)ks * PPN + (size_t)b * DD_ * DIM_;
#pragma unroll
    for (int i = 0; i < 8; ++i)
#pragma unroll
        for (int j = 0; j < 4; ++j)
#pragma unroll
            for (int r = 0; r < 4; ++r)
                O[(size_t)(row0 + i * 16 + q * 4 + r) * DIM_ +
                  col0 + j * 16 + c16] = __float2half(acc[i][j][r]);
}

// ---------------------------------------------------------------------------
// k_dvalW2: d_val[b*dd][e] = sum_d' (Σks Pp[ks][b*dd][d']) * Wv[d'][e]
// (absorbs reduceU; A = fp32-sum of 4 fp16 Pp slices -> f2bf, identical value
// chain; Wv transposed in-kernel with conflict-free packed b32 writes.)
// ---------------------------------------------------------------------------
__global__ __launch_bounds__(256) void k_dvalW2(const __half* __restrict__ Pp,
                                                const float* __restrict__ Wv,
                                                float* __restrict__ d_val) {
    __shared__ unsigned short As[2 * 128 * 32];
    __shared__ unsigned short Bs[2 * 128 * 32];
    const int n0 = blockIdx.x * 128, m0 = blockIdx.y * 128;
    const int t = threadIdx.x;
    const int rA = t >> 2, cA = ((t & 3) ^ ((t >> 3) & 3)) * 8;
    const __half* gA = Pp + (size_t)(m0 + rA) * DIM_ + cA;
    const int d0 = (t >> 4) * 2;      // [0,32) step 2 (K-local)
    const int ecol = t & 15;          // e = ecol + 16*i

    ACC_INIT
    auto stageA8 = [&](unsigned short* dst, const __half* g) {
        float o[8] = {0.f, 0.f, 0.f, 0.f, 0.f, 0.f, 0.f, 0.f};
#pragma unroll
        for (int ksl = 0; ksl < 4; ++ksl) {
            uint4 v = *(const uint4*)(g + (size_t)ksl * PPN);
            const __half* h = (const __half*)&v;
#pragma unroll
            for (int j = 0; j < 8; ++j) o[j] += __half2float(h[j]);
        }
        unsigned short tmp[8];
#pragma unroll
        for (int j = 0; j < 8; ++j) tmp[j] = f2bf(o[j]);
        *(uint4*)dst = *(const uint4*)tmp;
    };
    auto stage = [&](int buf, int kt) {
        const int o = buf * 4096;
        stageA8(&As[o + t * 8],        gA + kt * 32);
        stageA8(&As[o + 2048 + t * 8], gA + kt * 32 + (size_t)64 * DIM_);
        const float* wv = Wv + (size_t)(kt * 32 + d0) * DIM_ + n0 + ecol;
#pragma unroll
        for (int i = 0; i < 8; ++i) {
            float v0 = wv[16 * i];
            float v1 = wv[16 * i + DIM_];
            unsigned int pk = (unsigned int)f2bf(v0) | ((unsigned int)f2bf(v1) << 16);
            const int e = ecol + 16 * i;
            const int phys = e * 32 + (((d0 >> 3) ^ ((e >> 1) & 3)) << 3) + (d0 & 7);
            *(unsigned int*)&Bs[o + phys] = pk;
        }
    };

    stage(0, 0);
    __syncthreads();
    const int lane = t & 63, wave = t >> 6;
    const int mrow = (wave >> 1) * 64, ncol = (wave & 1) * 64;
    const int fr = lane & 15, fk = (lane >> 4) * 8;
    const int swz = (((fk >> 3) ^ ((fr >> 1) & 3)) << 3);
    for (int kt = 0; kt < DIM_ / 32; ++kt) {
        if (kt + 1 < DIM_ / 32) stage((kt + 1) & 1, kt + 1);
        const int cur = (kt & 1) * 4096;
        bf16x8 af[4], bfr[4];
#pragma unroll
        for (int i = 0; i < 4; ++i)
            af[i] = *(const bf16x8*)&As[cur + (mrow + i * 16 + fr) * 32 + swz];
#pragma unroll
        for (int j = 0; j < 4; ++j)
            bfr[j] = *(const bf16x8*)&Bs[cur + (ncol + j * 16 + fr) * 32 + swz];
#pragma unroll
        for (int i = 0; i < 4; ++i)
#pragma unroll
            for (int j = 0; j < 4; ++j)
                acc[i][j] = __builtin_amdgcn_mfma_f32_16x16x32_bf16(af[i], bfr[j],
                                                                    acc[i][j], 0, 0, 0);
        __syncthreads();
    }
    const int col = lane & 15, q = lane >> 4;
#pragma unroll
    for (int i = 0; i < 4; ++i)
#pragma unroll
        for (int j = 0; j < 4; ++j)
#pragma unroll
            for (int r = 0; r < 4; ++r)
                d_val[(size_t)(m0 + mrow + i * 16 + q * 4 + r) * DIM_ +
                      n0 + ncol + j * 16 + col] = acc[i][j][r];
}

// ---------------------------------------------------------------------------
extern "C" void kernel_launch(void* const* d_in, const int* in_sizes, int n_in,
                              void* d_out, int out_size, void* d_ws, size_t ws_size,
                              hipStream_t stream) {
    const float* src   = (const float*)d_in[0];   // [B,S,DIM]
    const float* state = (const float*)d_in[1];   // [B,S]
    const float* dst   = (const float*)d_in[2];   // [B,D,DIM]
    const float* Wr    = (const float*)d_in[3];   // [DIM,DIM]
    const float* Wv    = (const float*)d_in[4];   // [DIM,DIM]

    // ws layout (128 MiB):
    //  A [0,32):  srcb bf16 (prep -> mid); late: Pp fp16 4x8MiB (dU -> dvalW2)
    //  B [32,96): LT bf16 (logitsT -> dU, mid)
    //  C [96,128): early: DW(8MB) + Lpart(.5MB); late: srcST (32MB, mid -> dU)
    //  scale & w park in d_out's d_val region (dead until k_dvalW2 writes it)
    unsigned short* srcb = (unsigned short*)d_ws;
    __half* Pp = (__half*)d_ws;                                // overlays dead srcb
    unsigned short* LT = srcb + (size_t)B_ * S_ * DIM_;
    unsigned short* C = LT + (size_t)B_ * DD_ * S_;
    unsigned short* DW = C;
    float* Lpart = (float*)(DW + (size_t)B_ * DD_ * DIM_);     // [B][4][S]
    unsigned short* srcST = C;                                 // overlays dead DW/Lpart

    float* d_state = (float*)d_out;               // [B, DD]
    float* d_val   = (float*)d_out + B_ * DD_;    // [B, DD, DIM]
    float* scale   = d_val;                       // park (dead before k_dvalW2)
    float* w       = d_val + (size_t)B_ * S_;     // park, right after scale

    k_prep<<<dim3(8192), 256, 0, stream>>>(src, srcb);
    k_dstWr<<<dim3(DIM_ / 128, (B_ * DD_) / 128), 256, 0, stream>>>(dst, Wr, DW);
    k_logitsT<<<dim3(512), 512, 0, stream>>>(DW, srcb, LT, Lpart);
    k_finalize<<<dim3((B_ * S_) / 256), 256, 0, stream>>>(state, Lpart, scale, w);
    k_mid<<<dim3(2048 + 4096), 256, 0, stream>>>(LT, w, srcb, scale, srcST, d_state);
    k_dU<<<dim3(256), 512, 0, stream>>>(LT, srcST, Pp);
    k_dvalW2<<<dim3(DIM_ / 128, (B_ * DD_) / 128), 256, 0, stream>>>(Pp, Wv, d_val);
}